// Round 4
// baseline (296.345 us; speedup 1.0000x reference)
//
#include <hip/hip_runtime.h>
#include <hip/hip_bf16.h>

#define B_ 16
#define C_ 256
#define N_ 4096
#define CN_ (C_ * N_)   // 1048576

typedef __attribute__((ext_vector_type(8))) short bf16x8_t;
typedef __attribute__((ext_vector_type(8))) unsigned short u16x8_t;
typedef __attribute__((ext_vector_type(4))) float f32x4_t;
typedef unsigned int u32;
typedef unsigned short u16;

__device__ __forceinline__ u16 f2bf(float f) {
    __hip_bfloat16 h = __float2bfloat16(f);
    return __builtin_bit_cast(u16, h);
}
__device__ __forceinline__ float bf2f(u16 u) {
    return __builtin_bit_cast(float, (u32)u << 16);
}

// async global->LDS, 16B per lane; lds base wave-uniform (HW adds lane*16)
__device__ __forceinline__ void gl_lds16(const void* g, void* l) {
    __builtin_amdgcn_global_load_lds(
        (const __attribute__((address_space(1))) u32*)(g),
        (__attribute__((address_space(3))) u32*)(l), 16, 0, 0);
}

#define WAITV(N) asm volatile("s_waitcnt vmcnt(" #N ")" ::: "memory")
#define BAR()    do { __builtin_amdgcn_s_barrier(); asm volatile("" ::: "memory"); } while (0)

// ---------------- kernel 1: norms + bf16 normalize + sums ----------------
__global__ __launch_bounds__(256) void knorm(const float* __restrict__ x1,
                                             const float* __restrict__ x2,
                                             u16* __restrict__ x1n,
                                             u16* __restrict__ x2n,
                                             u16* __restrict__ sN,
                                             u16* __restrict__ sxb,
                                             float* __restrict__ norms) {
    __shared__ float sx1[4096];
    __shared__ float sx2[4096];
    int row = blockIdx.x;              // b*256 + c
    int t = threadIdx.x;
    const float4* r1 = (const float4*)(x1 + (size_t)row * N_);
    const float4* r2 = (const float4*)(x2 + (size_t)row * N_);
    float s1 = 0.f, s2 = 0.f;
#pragma unroll
    for (int p = 0; p < 4; ++p) {
        float4 a = r1[p * 256 + t];
        float4 b = r2[p * 256 + t];
        s1 += a.x * a.x + a.y * a.y + a.z * a.z + a.w * a.w;
        s2 += b.x * b.x + b.y * b.y + b.z * b.z + b.w * b.w;
        *(float4*)&sx1[(p * 256 + t) * 4] = a;
        *(float4*)&sx2[(p * 256 + t) * 4] = b;
    }
#pragma unroll
    for (int m = 32; m; m >>= 1) { s1 += __shfl_xor(s1, m); s2 += __shfl_xor(s2, m); }
    __shared__ float red[2][4];
    int wid = t >> 6;
    if ((t & 63) == 0) { red[0][wid] = s1; red[1][wid] = s2; }
    __syncthreads();
    s1 = red[0][0] + red[0][1] + red[0][2] + red[0][3];
    s2 = red[1][0] + red[1][1] + red[1][2] + red[1][3];
    float n1 = fmaxf(sqrtf(s1), 1e-12f);
    float n2 = fmaxf(sqrtf(s2), 1e-12f);
    if (t == 0) {
        int bb = row >> 8, cc = row & 255;
        norms[(bb * 2 + 0) * 256 + cc] = n1;
        norms[(bb * 2 + 1) * 256 + cc] = n2;
    }
    float i1 = 1.0f / n1, i2 = 1.0f / n2;
    const size_t rbase = (size_t)row * N_;
#pragma unroll
    for (int j = 0; j < 2; ++j) {
        int e = j * 2048 + t * 8;
        float a[8], b[8];
        *(float4*)&a[0] = *(const float4*)&sx1[e];
        *(float4*)&a[4] = *(const float4*)&sx1[e + 4];
        *(float4*)&b[0] = *(const float4*)&sx2[e];
        *(float4*)&b[4] = *(const float4*)&sx2[e + 4];
        u16x8_t w1, w2, ws, wr;
#pragma unroll
        for (int i = 0; i < 8; ++i) {
            float va = a[i] * i1, vb = b[i] * i2;
            w1[i] = f2bf(va);
            w2[i] = f2bf(vb);
            ws[i] = f2bf(va + vb);
            wr[i] = f2bf(a[i] + b[i]);
        }
        *(u16x8_t*)(x1n + rbase + e) = w1;
        *(u16x8_t*)(x2n + rbase + e) = w2;
        *(u16x8_t*)(sN  + rbase + e) = ws;
        *(u16x8_t*)(sxb + rbase + e) = wr;
    }
}

// ------ kernel 2: part[kc] = sN @ x{w}n^T over K-chunk (both w fused) -----
// 64c x 64d tile, K-split x4 (1024 each, 32 steps of BK=32).
// 3-buffer / 2-ahead gl_lds pipeline with counted vmcnt(3).
__global__ __launch_bounds__(256) void klogits(const u16* __restrict__ sN,
                                               const u16* __restrict__ x1n,
                                               const u16* __restrict__ x2n,
                                               float* __restrict__ part) {
    int bid = blockIdx.x;                 // 1024 blocks
    int xcd = bid & 7;
    int u = bid >> 3;                     // 0..127
    int b = xcd + 8 * (u & 1);
    int tile = (u >> 1) & 15;
    int kc4 = u >> 5;                     // 0..3 K-chunk
    int c0 = (tile & 3) * 64;
    int d0 = (tile >> 2) * 64;

    __shared__ u16 lds[3][6144];          // 3 bufs x 12KB (sN | x1n | x2n tiles)

    int t = threadIdx.x, lane = t & 63, wid = t >> 6;
    int w = wid & 1, chalf = wid >> 1;
    int lm = lane & 15;

    // staging: thread t handles chunk (r, colb) in each of the 3 tiles
    int r = t >> 2;
    int colb = ((t & 3) * 16) ^ ((r & 3) << 4);       // pre-swizzled source col
    const char* gsrc[3];
    gsrc[0] = (const char*)(sN  + (size_t)b * CN_ + (size_t)(c0 + r) * N_ + kc4 * 1024) + colb;
    gsrc[1] = (const char*)(x1n + (size_t)b * CN_ + (size_t)(d0 + r) * N_ + kc4 * 1024) + colb;
    gsrc[2] = (const char*)(x2n + (size_t)b * CN_ + (size_t)(d0 + r) * N_ + kc4 * 1024) + colb;
    int ldoff[3];
#pragma unroll
    for (int qq = 0; qq < 3; ++qq) ldoff[qq] = (t + 256 * qq) * 16;

#define STAGE_L(KS) do { \
        char* dst = (char*)&lds[(KS) % 3][0]; \
        _Pragma("unroll") \
        for (int qq = 0; qq < 3; ++qq) \
            gl_lds16(gsrc[qq] + (KS) * 64, dst + ldoff[qq]); \
    } while (0)

    f32x4_t acc[2][4];
#pragma unroll
    for (int i = 0; i < 2; ++i)
#pragma unroll
        for (int j = 0; j < 4; ++j) acc[i][j] = 0.f;

    int kh16 = (lane >> 4) * 16;
    int swz = (lm & 3) << 4;
    int aoff[2], boff[4];
#pragma unroll
    for (int mi = 0; mi < 2; ++mi)
        aoff[mi] = (chalf * 32 + mi * 16 + lm) * 64 + (kh16 ^ swz);
#pragma unroll
    for (int ni = 0; ni < 4; ++ni)
        boff[ni] = (1 + w) * 4096 + (ni * 16 + lm) * 64 + (kh16 ^ swz);

    STAGE_L(0);
    STAGE_L(1);
    WAITV(3);       // drain S0, keep S1
    BAR();

#pragma unroll
    for (int ks = 0; ks < 32; ++ks) {
        if (ks + 2 <= 31) STAGE_L(ks + 2);
        const char* base = (const char*)&lds[ks % 3][0];
        bf16x8_t af[2], bfr[4];
#pragma unroll
        for (int mi = 0; mi < 2; ++mi) af[mi] = *(const bf16x8_t*)(base + aoff[mi]);
#pragma unroll
        for (int ni = 0; ni < 4; ++ni) bfr[ni] = *(const bf16x8_t*)(base + boff[ni]);
#pragma unroll
        for (int mi = 0; mi < 2; ++mi)
#pragma unroll
            for (int ni = 0; ni < 4; ++ni)
                acc[mi][ni] = __builtin_amdgcn_mfma_f32_16x16x32_bf16(af[mi], bfr[ni], acc[mi][ni], 0, 0, 0);
        if (ks < 30) { WAITV(3); }
        else if (ks == 30) { WAITV(0); }
        if (ks < 31) BAR();
    }
#undef STAGE_L

    float* outp = part + ((((size_t)kc4 * 16 + b) * 2 + w) * 256 + c0 + chalf * 32) * 256 + d0;
    int orow = (lane >> 4) * 4, ocol = lane & 15;
#pragma unroll
    for (int mi = 0; mi < 2; ++mi)
#pragma unroll
        for (int ni = 0; ni < 4; ++ni)
#pragma unroll
            for (int rr = 0; rr < 4; ++rr)
                outp[(size_t)(mi * 16 + orow + rr) * 256 + ni * 16 + ocol] = acc[mi][ni][rr];
}

// ---- kernel 3: sum 4 K-partials, row softmax, fold norm[d], emit bf16 ----
__global__ __launch_bounds__(256) void ksoftmax(const float* __restrict__ part,
                                                const float* __restrict__ norms,
                                                u16* __restrict__ attnp) {
    const size_t S = 2097152;            // elems per K-chunk partial
    int rid = blockIdx.x * 4 + (threadIdx.x >> 6);   // (b*2+w)*256 + c
    int l = threadIdx.x & 63;
    int bw = rid >> 8, c = rid & 255;
    size_t rbase = (size_t)bw * 65536 + (size_t)c * 256;
    float v[4];
    float m = -1e30f;
#pragma unroll
    for (int j = 0; j < 4; ++j) {
        int d = j * 64 + l;
        v[j] = part[rbase + d] + part[rbase + S + d] +
               part[rbase + 2 * S + d] + part[rbase + 3 * S + d];
        m = fmaxf(m, v[j]);
    }
#pragma unroll
    for (int s = 32; s; s >>= 1) m = fmaxf(m, __shfl_xor(m, s));
    float sum = 0.f;
#pragma unroll
    for (int j = 0; j < 4; ++j) { v[j] = __expf(v[j] - m); sum += v[j]; }
#pragma unroll
    for (int s = 32; s; s >>= 1) sum += __shfl_xor(sum, s);
    float rs = 1.0f / sum;
    u16* outp = attnp + (size_t)rid * 256;
    const float* nr = norms + (size_t)bw * 256;
#pragma unroll
    for (int j = 0; j < 4; ++j)
        outp[j * 64 + l] = f2bf(v[j] * rs * nr[j * 64 + l]);
}

// -------- kernel 3.5: transpose x{w}n (c-major) -> xT{w} (n-major) --------
// 64x64 tiles, both tensors per block; pack4 LDS transpose (XOR-swizzled).
__global__ __launch_bounds__(256) void ktrans(const u16* __restrict__ x1n,
                                              const u16* __restrict__ x2n,
                                              u16* __restrict__ xT1,
                                              u16* __restrict__ xT2) {
    int bid = blockIdx.x;              // 4096 blocks
    int xcd = bid & 7;
    int u = bid >> 3;                  // 0..511
    int b = xcd + 8 * (u & 1);
    int rest = u >> 1;                 // 0..255
    int ct = rest & 3, nt = rest >> 2; // 4 c-tiles, 64 n-tiles
    int n0 = nt * 64, c0 = ct * 64;

    __shared__ u16 sT[2][4096];        // [tensor][64n x 64c] swizzled

    int t = threadIdx.x;
    int tensorA = t >> 7;
    int tt = t & 127;
    int dq = (tt & 15) * 4;            // 4 consecutive c rows
    int n8 = (tt >> 4) * 8;            // 8 consecutive n cols
    const u16* src = (tensorA ? x2n : x1n) + (size_t)b * CN_ + n0 + n8;

    uint4 r0 = *(const uint4*)(src + (size_t)(c0 + dq + 0) * N_);
    uint4 r1 = *(const uint4*)(src + (size_t)(c0 + dq + 1) * N_);
    uint4 r2 = *(const uint4*)(src + (size_t)(c0 + dq + 2) * N_);
    uint4 r3 = *(const uint4*)(src + (size_t)(c0 + dq + 3) * N_);
    const u16* p0 = (const u16*)&r0;
    const u16* p1 = (const u16*)&r1;
    const u16* p2 = (const u16*)&r2;
    const u16* p3 = (const u16*)&r3;
    char* dst = (char*)&sT[tensorA][0];
#pragma unroll
    for (int i = 0; i < 8; ++i) {
        u32 lo = (u32)p0[i] | ((u32)p1[i] << 16);
        u32 hi = (u32)p2[i] | ((u32)p3[i] << 16);
        int n = n8 + i;
        int addr = (n << 7) + ((dq << 1) ^ ((n & 7) << 4));
        uint2 val; val.x = lo; val.y = hi;
        *(uint2*)(dst + addr) = val;
    }
    __syncthreads();

    u16* out = (tensorA ? xT2 : xT1) + (size_t)b * CN_;
    const char* sbase = (const char*)&sT[tensorA][0];
#pragma unroll
    for (int j = 0; j < 4; ++j) {
        int n = (tt >> 3) + j * 16;
        int c16b = (tt & 7) * 16;
        uint4 v = *(const uint4*)(sbase + (n << 7) + (c16b ^ ((n & 7) << 4)));
        *(uint4*)(out + (size_t)(n0 + n) * 256 + c0 + (c16b >> 1)) = v;
    }
}

// ------- kernel 4: out[n,c] = yT1 + yT2 + (x1+x2) (fused both which) ------
// A from n-major xT via gl_lds (3-buf counted pipeline, 2-tensor interleave);
// B (attn) register-prefetched from L2; epilogue adds bf16 residual.
__global__ __launch_bounds__(256) void kout(const u16* __restrict__ xT1,
                                            const u16* __restrict__ xT2,
                                            const u16* __restrict__ attnp,
                                            const u16* __restrict__ sxb,
                                            float* __restrict__ out) {
    int bid = blockIdx.x;              // 2048 blocks
    int xcd = bid & 7;
    int u = bid >> 3;                  // 0..255
    int b = xcd + 8 * (u & 1);
    int rest = u >> 1;                 // 0..127
    int nt = rest >> 2;                // 0..31 -> 128 rows each
    int cs = rest & 3;                 // 0..3  -> 64 cols each
    int n0 = nt * 128, c0 = cs * 64;

    __shared__ u16 lds[3][8192];       // 3 bufs x 16KB: [128n][T0 32d | T1 32d]

    int t = threadIdx.x, lane = t & 63, wid = t >> 6;
    int wm = wid >> 1, wc2 = wid & 1;  // wave: 64n x 32c
    int lm = lane & 15;
    int kh16 = (lane >> 4) * 16;

    // A staging: thread t handles 4 chunks q = t + 256*qq
    const u16* xTt[2] = { xT1 + (size_t)b * CN_, xT2 + (size_t)b * CN_ };
    const char* gA[4];
    int ldA[4];
#pragma unroll
    for (int qq = 0; qq < 4; ++qq) {
        int q = t + 256 * qq;
        int r = q >> 3;
        int colb = ((q & 7) * 16) ^ ((r & 7) << 4);   // pre-swizzled combined col
        int T = colb >> 6, k8 = (colb >> 4) & 3;
        gA[qq] = (const char*)(xTt[T] + (size_t)(n0 + r) * 256 + k8 * 8);
        ldA[qq] = q * 16;
    }
#define STAGE_A(KS) do { \
        char* dstl = (char*)&lds[(KS) % 3][0]; \
        _Pragma("unroll") \
        for (int qq = 0; qq < 4; ++qq) \
            gl_lds16(gA[qq] + (KS) * 64, dstl + ldA[qq]); \
    } while (0)

    // B prefetch pointers: [T][ci], 16B per step at +ks*64
    const char* bptr[2][2];
#pragma unroll
    for (int T = 0; T < 2; ++T)
#pragma unroll
        for (int ci = 0; ci < 2; ++ci)
            bptr[T][ci] = (const char*)(attnp +
                ((size_t)(b * 2 + T) * 256 + c0 + wc2 * 32 + ci * 16 + lm) * 256) + kh16;

    uint4 brA[4], brB[4];              // two B register sets [T*2+ci]
#define BLOAD(SET, KS) do { \
        _Pragma("unroll") \
        for (int T = 0; T < 2; ++T) \
            _Pragma("unroll") \
            for (int ci = 0; ci < 2; ++ci) \
                SET[T * 2 + ci] = *(const uint4*)(bptr[T][ci] + (KS) * 64); \
    } while (0)

    f32x4_t acc1[4][2], acc2[4][2];
#pragma unroll
    for (int i = 0; i < 4; ++i)
#pragma unroll
        for (int j = 0; j < 2; ++j) { acc1[i][j] = 0.f; acc2[i][j] = 0.f; }

    int swz = (lm & 7) << 4;
    int aoff[2][4];
#pragma unroll
    for (int T = 0; T < 2; ++T)
#pragma unroll
        for (int mi = 0; mi < 4; ++mi)
            aoff[T][mi] = (wm * 64 + mi * 16 + lm) * 128 + ((T * 64 + kh16) ^ swz);

    // prologue: S0, B0, S1; drain S0 (keep B0,S1)
    STAGE_A(0);
    BLOAD(brA, 0);
    STAGE_A(1);
    WAITV(8);
    BAR();

#pragma unroll
    for (int ks = 0; ks < 8; ++ks) {
        if (ks + 1 <= 7) {
            if (ks & 1) BLOAD(brA, ks + 1); else BLOAD(brB, ks + 1);
        }
        if (ks + 2 <= 7) STAGE_A(ks + 2);
        const char* base = (const char*)&lds[ks % 3][0];
        const uint4* bcur = (ks & 1) ? brB : brA;
        bf16x8_t a1f[4], a2f[4];
#pragma unroll
        for (int mi = 0; mi < 4; ++mi) {
            a1f[mi] = *(const bf16x8_t*)(base + aoff[0][mi]);
            a2f[mi] = *(const bf16x8_t*)(base + aoff[1][mi]);
        }
#pragma unroll
        for (int mi = 0; mi < 4; ++mi)
#pragma unroll
            for (int ci = 0; ci < 2; ++ci) {
                acc1[mi][ci] = __builtin_amdgcn_mfma_f32_16x16x32_bf16(
                    a1f[mi], __builtin_bit_cast(bf16x8_t, bcur[0 * 2 + ci]), acc1[mi][ci], 0, 0, 0);
                acc2[mi][ci] = __builtin_amdgcn_mfma_f32_16x16x32_bf16(
                    a2f[mi], __builtin_bit_cast(bf16x8_t, bcur[1 * 2 + ci]), acc2[mi][ci], 0, 0, 0);
            }
        if (ks < 6) { WAITV(8); }
        else if (ks == 6) { WAITV(4); }
        if (ks < 7) BAR();
    }
#undef STAGE_A
#undef BLOAD

    const size_t obase = (size_t)b * CN_;
    int orow = (lane >> 4) * 4, ocol = lane & 15;
#pragma unroll
    for (int mi = 0; mi < 4; ++mi)
#pragma unroll
        for (int ci = 0; ci < 2; ++ci)
#pragma unroll
            for (int rr = 0; rr < 4; ++rr) {
                int n = n0 + wm * 64 + mi * 16 + orow + rr;
                int c = c0 + wc2 * 32 + ci * 16 + ocol;
                size_t f = obase + (size_t)n * 256 + c;
                out[f] = acc1[mi][ci][rr] + acc2[mi][ci][rr] + bf2f(sxb[f]);
            }
}

// --------------------------------- launch ---------------------------------
extern "C" void kernel_launch(void* const* d_in, const int* in_sizes, int n_in,
                              void* d_out, int out_size, void* d_ws, size_t ws_size,
                              hipStream_t stream) {
    const float* x1 = (const float*)d_in[0];
    const float* x2 = (const float*)d_in[1];
    float* out = (float*)d_out;

    char* ws = (char*)d_ws;
    u16*   x1n   = (u16*)(ws);                         // 32 MB
    u16*   x2n   = (u16*)(ws + 33554432ull);           // 32 MB
    u16*   sN    = (u16*)(ws + 67108864ull);           // 32 MB (xT1 after klogits)
    u16*   sxb   = (u16*)(ws + 100663296ull);          // 32 MB
    float* part  = (float*)(ws + 134217728ull);        // 32 MB (xT2 after ksoftmax)
    u16*   attnp = (u16*)(ws + 167772160ull);          //  4 MB
    float* norms = (float*)(ws + 171966464ull);        // 32 KB

    u16* xT1 = (u16*)sN;        // overlay: sN dead after klogits
    u16* xT2 = (u16*)part;      // overlay: part dead after ksoftmax

    knorm<<<4096, 256, 0, stream>>>(x1, x2, x1n, x2n, sN, sxb, norms);
    klogits<<<1024, 256, 0, stream>>>(sN, x1n, x2n, part);
    ksoftmax<<<2048, 256, 0, stream>>>(part, norms, attnp);
    ktrans<<<4096, 256, 0, stream>>>(x1n, x2n, xT1, xT2);
    kout<<<2048, 256, 0, stream>>>(xT1, xT2, attnp, sxb, out);
}

// Round 5
// 268.813 us; speedup vs baseline: 1.1024x; 1.1024x over previous
//
#include <hip/hip_runtime.h>
#include <hip/hip_bf16.h>

#define B_ 16
#define C_ 256
#define N_ 4096
#define CN_ (C_ * N_)   // 1048576

typedef __attribute__((ext_vector_type(8))) short bf16x8_t;
typedef __attribute__((ext_vector_type(8))) unsigned short u16x8_t;
typedef __attribute__((ext_vector_type(4))) float f32x4_t;
typedef unsigned int u32;
typedef unsigned short u16;

__device__ __forceinline__ u16 f2bf(float f) {
    __hip_bfloat16 h = __float2bfloat16(f);
    return __builtin_bit_cast(u16, h);
}
__device__ __forceinline__ float bf2f(u16 u) {
    return __builtin_bit_cast(float, (u32)u << 16);
}

// async global->LDS, 16B per lane; lds base wave-uniform (HW adds lane*16)
__device__ __forceinline__ void gl_lds16(const void* g, void* l) {
    __builtin_amdgcn_global_load_lds(
        (const __attribute__((address_space(1))) u32*)(g),
        (__attribute__((address_space(3))) u32*)(l), 16, 0, 0);
}

#define WAITV(N) asm volatile("s_waitcnt vmcnt(" #N ")" ::: "memory")
#define BAR()    do { __builtin_amdgcn_s_barrier(); asm volatile("" ::: "memory"); } while (0)

// ---------------- kernel 1: norms + bf16 normalize + sums ----------------
__global__ __launch_bounds__(256) void knorm(const float* __restrict__ x1,
                                             const float* __restrict__ x2,
                                             u16* __restrict__ x1n,
                                             u16* __restrict__ x2n,
                                             u16* __restrict__ sN,
                                             u16* __restrict__ sxb,
                                             float* __restrict__ norms) {
    __shared__ float sx1[4096];
    __shared__ float sx2[4096];
    int row = blockIdx.x;              // b*256 + c
    int t = threadIdx.x;
    const float4* r1 = (const float4*)(x1 + (size_t)row * N_);
    const float4* r2 = (const float4*)(x2 + (size_t)row * N_);
    float s1 = 0.f, s2 = 0.f;
#pragma unroll
    for (int p = 0; p < 4; ++p) {
        float4 a = r1[p * 256 + t];
        float4 b = r2[p * 256 + t];
        s1 += a.x * a.x + a.y * a.y + a.z * a.z + a.w * a.w;
        s2 += b.x * b.x + b.y * b.y + b.z * b.z + b.w * b.w;
        *(float4*)&sx1[(p * 256 + t) * 4] = a;
        *(float4*)&sx2[(p * 256 + t) * 4] = b;
    }
#pragma unroll
    for (int m = 32; m; m >>= 1) { s1 += __shfl_xor(s1, m); s2 += __shfl_xor(s2, m); }
    __shared__ float red[2][4];
    int wid = t >> 6;
    if ((t & 63) == 0) { red[0][wid] = s1; red[1][wid] = s2; }
    __syncthreads();
    s1 = red[0][0] + red[0][1] + red[0][2] + red[0][3];
    s2 = red[1][0] + red[1][1] + red[1][2] + red[1][3];
    float n1 = fmaxf(sqrtf(s1), 1e-12f);
    float n2 = fmaxf(sqrtf(s2), 1e-12f);
    if (t == 0) {
        int bb = row >> 8, cc = row & 255;
        norms[(bb * 2 + 0) * 256 + cc] = n1;
        norms[(bb * 2 + 1) * 256 + cc] = n2;
    }
    float i1 = 1.0f / n1, i2 = 1.0f / n2;
    const size_t rbase = (size_t)row * N_;
#pragma unroll
    for (int j = 0; j < 2; ++j) {
        int e = j * 2048 + t * 8;
        float a[8], b[8];
        *(float4*)&a[0] = *(const float4*)&sx1[e];
        *(float4*)&a[4] = *(const float4*)&sx1[e + 4];
        *(float4*)&b[0] = *(const float4*)&sx2[e];
        *(float4*)&b[4] = *(const float4*)&sx2[e + 4];
        u16x8_t w1, w2, ws, wr;
#pragma unroll
        for (int i = 0; i < 8; ++i) {
            float va = a[i] * i1, vb = b[i] * i2;
            w1[i] = f2bf(va);
            w2[i] = f2bf(vb);
            ws[i] = f2bf(va + vb);
            wr[i] = f2bf(a[i] + b[i]);
        }
        *(u16x8_t*)(x1n + rbase + e) = w1;
        *(u16x8_t*)(x2n + rbase + e) = w2;
        *(u16x8_t*)(sN  + rbase + e) = ws;
        *(u16x8_t*)(sxb + rbase + e) = wr;
    }
}

// ------ kernel 2: part[kc] = sN @ x{w}n^T over K-chunk (both w fused) -----
// 64c x 64d tile, K-split x4 (1024 each, 32 steps of BK=32).
// bid decode: consecutive per-XCD blocks share one (b,kc) group -> L2 reuse.
__global__ __launch_bounds__(256) void klogits(const u16* __restrict__ sN,
                                               const u16* __restrict__ x1n,
                                               const u16* __restrict__ x2n,
                                               float* __restrict__ part) {
    int bid = blockIdx.x;                 // 1024 blocks
    int xcd = bid & 7;
    int u = bid >> 3;                     // 0..127
    int tile = u & 15;                    // fastest: 16 tiles of one (b,kc)
    int g = u >> 4;                       // 0..7
    int b = xcd + 8 * (g & 1);
    int kc4 = g >> 1;                     // 0..3 K-chunk
    int c0 = (tile & 3) * 64;
    int d0 = (tile >> 2) * 64;

    __shared__ u16 lds[3][6144];          // 3 bufs x 12KB (sN | x1n | x2n tiles)

    int t = threadIdx.x, lane = t & 63, wid = t >> 6;
    int w = wid & 1, chalf = wid >> 1;
    int lm = lane & 15;

    int r = t >> 2;
    int colb = ((t & 3) * 16) ^ ((r & 3) << 4);       // pre-swizzled source col
    const char* gsrc[3];
    gsrc[0] = (const char*)(sN  + (size_t)b * CN_ + (size_t)(c0 + r) * N_ + kc4 * 1024) + colb;
    gsrc[1] = (const char*)(x1n + (size_t)b * CN_ + (size_t)(d0 + r) * N_ + kc4 * 1024) + colb;
    gsrc[2] = (const char*)(x2n + (size_t)b * CN_ + (size_t)(d0 + r) * N_ + kc4 * 1024) + colb;
    int ldoff[3];
#pragma unroll
    for (int qq = 0; qq < 3; ++qq) ldoff[qq] = (t + 256 * qq) * 16;

#define STAGE_L(KS) do { \
        char* dst = (char*)&lds[(KS) % 3][0]; \
        _Pragma("unroll") \
        for (int qq = 0; qq < 3; ++qq) \
            gl_lds16(gsrc[qq] + (KS) * 64, dst + ldoff[qq]); \
    } while (0)

    f32x4_t acc[2][4];
#pragma unroll
    for (int i = 0; i < 2; ++i)
#pragma unroll
        for (int j = 0; j < 4; ++j) acc[i][j] = 0.f;

    int kh16 = (lane >> 4) * 16;
    int swz = (lm & 3) << 4;
    int aoff[2], boff[4];
#pragma unroll
    for (int mi = 0; mi < 2; ++mi)
        aoff[mi] = (chalf * 32 + mi * 16 + lm) * 64 + (kh16 ^ swz);
#pragma unroll
    for (int ni = 0; ni < 4; ++ni)
        boff[ni] = (1 + w) * 4096 + (ni * 16 + lm) * 64 + (kh16 ^ swz);

    STAGE_L(0);
    STAGE_L(1);
    WAITV(3);       // drain S0, keep S1
    BAR();

#pragma unroll
    for (int ks = 0; ks < 32; ++ks) {
        if (ks + 2 <= 31) STAGE_L(ks + 2);
        const char* base = (const char*)&lds[ks % 3][0];
        bf16x8_t af[2], bfr[4];
#pragma unroll
        for (int mi = 0; mi < 2; ++mi) af[mi] = *(const bf16x8_t*)(base + aoff[mi]);
#pragma unroll
        for (int ni = 0; ni < 4; ++ni) bfr[ni] = *(const bf16x8_t*)(base + boff[ni]);
#pragma unroll
        for (int mi = 0; mi < 2; ++mi)
#pragma unroll
            for (int ni = 0; ni < 4; ++ni)
                acc[mi][ni] = __builtin_amdgcn_mfma_f32_16x16x32_bf16(af[mi], bfr[ni], acc[mi][ni], 0, 0, 0);
        if (ks < 30) { WAITV(3); }
        else if (ks == 30) { WAITV(0); }
        if (ks < 31) BAR();
    }
#undef STAGE_L

    float* outp = part + ((((size_t)kc4 * 16 + b) * 2 + w) * 256 + c0 + chalf * 32) * 256 + d0;
    int orow = (lane >> 4) * 4, ocol = lane & 15;
#pragma unroll
    for (int mi = 0; mi < 2; ++mi)
#pragma unroll
        for (int ni = 0; ni < 4; ++ni)
#pragma unroll
            for (int rr = 0; rr < 4; ++rr)
                outp[(size_t)(mi * 16 + orow + rr) * 256 + ni * 16 + ocol] = acc[mi][ni][rr];
}

// ---- kernel 3: sum 4 K-partials, row softmax, fold norm[d], emit bf16 ----
__global__ __launch_bounds__(256) void ksoftmax(const float* __restrict__ part,
                                                const float* __restrict__ norms,
                                                u16* __restrict__ attnp) {
    const size_t S = 2097152;            // elems per K-chunk partial
    int rid = blockIdx.x * 4 + (threadIdx.x >> 6);   // (b*2+w)*256 + c
    int l = threadIdx.x & 63;
    int bw = rid >> 8, c = rid & 255;
    size_t rbase = (size_t)bw * 65536 + (size_t)c * 256;
    float v[4];
    float m = -1e30f;
#pragma unroll
    for (int j = 0; j < 4; ++j) {
        int d = j * 64 + l;
        v[j] = part[rbase + d] + part[rbase + S + d] +
               part[rbase + 2 * S + d] + part[rbase + 3 * S + d];
        m = fmaxf(m, v[j]);
    }
#pragma unroll
    for (int s = 32; s; s >>= 1) m = fmaxf(m, __shfl_xor(m, s));
    float sum = 0.f;
#pragma unroll
    for (int j = 0; j < 4; ++j) { v[j] = __expf(v[j] - m); sum += v[j]; }
#pragma unroll
    for (int s = 32; s; s >>= 1) sum += __shfl_xor(sum, s);
    float rs = 1.0f / sum;
    u16* outp = attnp + (size_t)rid * 256;
    const float* nr = norms + (size_t)bw * 256;
#pragma unroll
    for (int j = 0; j < 4; ++j)
        outp[j * 64 + l] = f2bf(v[j] * rs * nr[j * 64 + l]);
}

// ------- kernel 4: out[n,c] = yT1 + yT2 + (x1+x2) (fused both which) ------
// Tile 128n x 64c, K=256 (d), BK=32, 8 steps, double-buffered.
// A: fused pack4 transpose x{w}n[d][n] -> LDS [n][8-slot swizzled 128B rows].
// B: attn rows via gl_lds with inverse-swizzled per-lane sources (L2-resident).
// LDS slot layout (A and B): row r has 8 slots of 16B; slot index s = T*4+dslot
// stored at position s ^ (r&7); slot content = 8 consecutive bf16 along d.
__global__ __launch_bounds__(256) void kout(const u16* __restrict__ x1n,
                                            const u16* __restrict__ x2n,
                                            const u16* __restrict__ attnp,
                                            const u16* __restrict__ sxb,
                                            float* __restrict__ out) {
    int bid = blockIdx.x;              // 2048 blocks
    int xcd = bid & 7;
    int j = bid >> 3;                  // 0..255
    int b = xcd + 8 * (j >> 7);        // same b for 128 consecutive per-XCD
    int j2 = j & 127;
    int nt = j2 >> 2, cs = j2 & 3;     // cs fastest: A-slice L2 reuse
    int n0 = nt * 128, c0 = cs * 64;

    __shared__ char ldsA[2][16384];    // [buf][128 n-rows][128B]
    __shared__ char ldsB[2][8192];     // [buf][ 64 c-rows][128B]

    int t = threadIdx.x, lane = t & 63, wid = t >> 6;
    int wm = wid >> 1, wc2 = wid & 1;  // wave: 64n x 32c
    int lm = lane & 15, lq = lane >> 4;

    // ---- A staging decode (pack4 transpose) ----
    int T_A = t >> 7;                  // 2 waves per tensor
    int tt = t & 127;
    int dq = (tt & 7) * 4;             // d-local 4-row group (0..28)
    int n8 = (tt >> 3) * 8;            // n-local 8 cols
    const u16* Asrc = (T_A ? x2n : x1n) + (size_t)b * CN_ + n0 + n8 + (size_t)dq * N_;

    // ---- B staging decode (2 gl_lds issues per thread) ----
    const char* Bsrc[2];
    int Bldoff[2];
#pragma unroll
    for (int q = 0; q < 2; ++q) {
        int c = q * 32 + (t >> 3);             // c-local row
        int s = (t & 7) ^ (c & 7);             // content slot for this position
        int T = s >> 2, dsl = s & 3;
        Bsrc[q] = (const char*)(attnp + ((size_t)(b * 2 + T) * 65536
                 + (size_t)(c0 + c) * 256 + dsl * 8));
        Bldoff[q] = q * 4096 + t * 16;
    }

    // ---- fragment read offsets (conflict-free swizzled) ----
    int aoff[2][4], boff[2][2];
#pragma unroll
    for (int T = 0; T < 2; ++T) {
#pragma unroll
        for (int mi = 0; mi < 4; ++mi)
            aoff[T][mi] = (wm * 64 + mi * 16 + lm) * 128
                        + (((T * 4 + lq) ^ (lm & 7)) << 4);
#pragma unroll
        for (int ci = 0; ci < 2; ++ci)
            boff[T][ci] = (wc2 * 32 + ci * 16 + lm) * 128
                        + (((T * 4 + lq) ^ (lm & 7)) << 4);
    }

    f32x4_t acc1[4][2], acc2[4][2];
#pragma unroll
    for (int i = 0; i < 4; ++i)
#pragma unroll
        for (int jj = 0; jj < 2; ++jj) { acc1[i][jj] = 0.f; acc2[i][jj] = 0.f; }

    uint4 r0, r1, r2, r3;
#define LOADA(KS) do { \
        size_t off = (size_t)(KS) * 32 * N_; \
        r0 = *(const uint4*)(Asrc + off); \
        r1 = *(const uint4*)(Asrc + off + N_); \
        r2 = *(const uint4*)(Asrc + off + 2 * N_); \
        r3 = *(const uint4*)(Asrc + off + 3 * N_); \
    } while (0)
#define STAGEB(KS, BUF) do { \
        _Pragma("unroll") \
        for (int q = 0; q < 2; ++q) \
            gl_lds16(Bsrc[q] + (KS) * 64, &ldsB[BUF][0] + Bldoff[q]); \
    } while (0)
#define WRITEA(BUF) do { \
        const u16* p0 = (const u16*)&r0; \
        const u16* p1 = (const u16*)&r1; \
        const u16* p2 = (const u16*)&r2; \
        const u16* p3 = (const u16*)&r3; \
        char* dst = &ldsA[BUF][0]; \
        _Pragma("unroll") \
        for (int i = 0; i < 8; ++i) { \
            u32 lo = (u32)p0[i] | ((u32)p1[i] << 16); \
            u32 hi = (u32)p2[i] | ((u32)p3[i] << 16); \
            int n = n8 + i; \
            int addr = (n << 7) + ((((T_A * 4 + (dq >> 3)) ^ (n & 7)) << 4) + (dq & 4) * 2); \
            uint2 val; val.x = lo; val.y = hi; \
            *(uint2*)(dst + addr) = val; \
        } \
    } while (0)

    // prologue: stage step 0
    STAGEB(0, 0);
    LOADA(0);
    WRITEA(0);
    __syncthreads();

    for (int ks = 0; ks < 8; ++ks) {
        int pp = ks & 1;
        if (ks < 7) {                   // issue next-step loads early (T14)
            STAGEB(ks + 1, pp ^ 1);
            LOADA(ks + 1);
        }
        const char* A = &ldsA[pp][0];
        const char* Bb = &ldsB[pp][0];
        bf16x8_t a1f[4], a2f[4], b1f[2], b2f[2];
#pragma unroll
        for (int mi = 0; mi < 4; ++mi) {
            a1f[mi] = *(const bf16x8_t*)(A + aoff[0][mi]);
            a2f[mi] = *(const bf16x8_t*)(A + aoff[1][mi]);
        }
#pragma unroll
        for (int ci = 0; ci < 2; ++ci) {
            b1f[ci] = *(const bf16x8_t*)(Bb + boff[0][ci]);
            b2f[ci] = *(const bf16x8_t*)(Bb + boff[1][ci]);
        }
#pragma unroll
        for (int mi = 0; mi < 4; ++mi)
#pragma unroll
            for (int ci = 0; ci < 2; ++ci) {
                acc1[mi][ci] = __builtin_amdgcn_mfma_f32_16x16x32_bf16(a1f[mi], b1f[ci], acc1[mi][ci], 0, 0, 0);
                acc2[mi][ci] = __builtin_amdgcn_mfma_f32_16x16x32_bf16(a2f[mi], b2f[ci], acc2[mi][ci], 0, 0, 0);
            }
        if (ks < 7) WRITEA(pp ^ 1);     // data-dep waits the global loads
        __syncthreads();                // drains gl_lds (B) + makes A visible
    }
#undef LOADA
#undef STAGEB
#undef WRITEA

    const size_t obase = (size_t)b * CN_;
#pragma unroll
    for (int mi = 0; mi < 4; ++mi)
#pragma unroll
        for (int ci = 0; ci < 2; ++ci)
#pragma unroll
            for (int rr = 0; rr < 4; ++rr) {
                int n = n0 + wm * 64 + mi * 16 + lq * 4 + rr;
                int c = c0 + wc2 * 32 + ci * 16 + lm;
                size_t f = obase + (size_t)n * 256 + c;
                out[f] = acc1[mi][ci][rr] + acc2[mi][ci][rr] + bf2f(sxb[f]);
            }
}

// --------------------------------- launch ---------------------------------
extern "C" void kernel_launch(void* const* d_in, const int* in_sizes, int n_in,
                              void* d_out, int out_size, void* d_ws, size_t ws_size,
                              hipStream_t stream) {
    const float* x1 = (const float*)d_in[0];
    const float* x2 = (const float*)d_in[1];
    float* out = (float*)d_out;

    char* ws = (char*)d_ws;
    u16*   x1n   = (u16*)(ws);                         // 32 MB
    u16*   x2n   = (u16*)(ws + 33554432ull);           // 32 MB
    u16*   sN    = (u16*)(ws + 67108864ull);           // 32 MB
    u16*   sxb   = (u16*)(ws + 100663296ull);          // 32 MB
    float* part  = (float*)(ws + 134217728ull);        // 32 MB (4 x 8MB K-partials)
    u16*   attnp = (u16*)(ws + 167772160ull);          //  4 MB
    float* norms = (float*)(ws + 171966464ull);        // 32 KB

    knorm<<<4096, 256, 0, stream>>>(x1, x2, x1n, x2n, sN, sxb, norms);
    klogits<<<1024, 256, 0, stream>>>(sN, x1n, x2n, part);
    ksoftmax<<<2048, 256, 0, stream>>>(part, norms, attnp);
    kout<<<2048, 256, 0, stream>>>(x1n, x2n, attnp, sxb, out);
}